// Round 1
// baseline (438.220 us; speedup 1.0000x reference)
//
#include <hip/hip_runtime.h>

#define D 128
#define NEG_SLOPE 0.2f

// ---------------- CSR build ----------------

__global__ void hist_kernel(const int* __restrict__ dst, int E, int N, int* __restrict__ deg) {
  int i = blockIdx.x * blockDim.x + threadIdx.x;
  if (i >= E + N) return;
  int d = (i < E) ? dst[i] : (i - E);
  atomicAdd(&deg[d], 1);
}

__global__ void scan_kernel(const int* __restrict__ deg, int* __restrict__ off, int N) {
  __shared__ int part[1024];
  int t = threadIdx.x;
  int C = (N + 1023) / 1024;
  int b = t * C;
  int e = min(b + C, N);
  int s = 0;
  for (int i = b; i < e; ++i) s += deg[i];
  part[t] = s;
  __syncthreads();
  for (int o = 1; o < 1024; o <<= 1) {
    int v = (t >= o) ? part[t - o] : 0;
    __syncthreads();
    part[t] += v;
    __syncthreads();
  }
  int base = (t == 0) ? 0 : part[t - 1];
  for (int i = b; i < e; ++i) { off[i] = base; base += deg[i]; }
  if (e == N && b < N) off[N] = base;
}

__global__ void scatter_kernel(const int* __restrict__ src, const int* __restrict__ dst,
                               int E, int N, const int* __restrict__ off,
                               int* __restrict__ cur, int* __restrict__ csr) {
  int i = blockIdx.x * blockDim.x + threadIdx.x;
  if (i >= E + N) return;
  int s, d;
  if (i < E) { s = src[i]; d = dst[i]; } else { s = i - E; d = s; }
  int pos = off[d] + atomicAdd(&cur[d], 1);
  csr[pos] = s;
}

// ---------------- fused GEMM + attention-score epilogue ----------------
// h = X @ W ; s_src = h @ a_src ; s_dst = h @ a_dst
// block = 128 threads (2 waves), tile = 64 rows x 128 cols, K in 2 chunks of 64.
// A staged TRANSPOSED in LDS (At[k][m], stride 68 -> conflict-free b128 reads).

__global__ __launch_bounds__(128) void gemm_fused(
    const float* __restrict__ X, const float* __restrict__ W,
    const float* __restrict__ avs, const float* __restrict__ avd,
    float* __restrict__ H, float* __restrict__ Ss, float* __restrict__ Sd, int N)
{
  __shared__ float At[64 * 68];   // [k2][m]
  __shared__ float Ws[64 * 128];  // [k2][n]
  int tid = threadIdx.x;
  int tx = tid & 15, ty = tid >> 4;     // tx: col group (16), ty: row group (8)
  int row0 = blockIdx.x * 64;

  float acc[8][8];
  #pragma unroll
  for (int i = 0; i < 8; ++i)
    #pragma unroll
    for (int j = 0; j < 8; ++j) acc[i][j] = 0.f;

  float as_[8], ad_[8];
  #pragma unroll
  for (int j = 0; j < 8; ++j) { as_[j] = avs[tx * 8 + j]; ad_[j] = avd[tx * 8 + j]; }

  for (int kc = 0; kc < 2; ++kc) {
    // stage A chunk transposed: 64 rows x 64 k
    #pragma unroll
    for (int it = 0; it < 16; ++it) {
      int lin = it * 128 + tid;        // float2 index, 0..2047
      int r = lin >> 5;                // 0..63
      int c2 = lin & 31;               // k pair
      int gr = row0 + r;
      float2 v = make_float2(0.f, 0.f);
      if (gr < N) v = *(const float2*)&X[(size_t)gr * D + kc * 64 + c2 * 2];
      At[(c2 * 2) * 68 + r] = v.x;
      At[(c2 * 2 + 1) * 68 + r] = v.y;
    }
    // stage W chunk: 64 k x 128 n
    #pragma unroll
    for (int it = 0; it < 16; ++it) {
      int lin = it * 128 + tid;        // float4 index, 0..2047
      int r = lin >> 5;                // 0..63 (k)
      int c4 = lin & 31;
      *(float4*)&Ws[r * 128 + c4 * 4] =
          *(const float4*)&W[(size_t)(kc * 64 + r) * D + c4 * 4];
    }
    __syncthreads();
    #pragma unroll 4
    for (int k = 0; k < 64; ++k) {
      float4 a0 = *(const float4*)&At[k * 68 + ty * 8];
      float4 a1 = *(const float4*)&At[k * 68 + ty * 8 + 4];
      float4 w0 = *(const float4*)&Ws[k * 128 + tx * 8];
      float4 w1 = *(const float4*)&Ws[k * 128 + tx * 8 + 4];
      float a[8] = {a0.x, a0.y, a0.z, a0.w, a1.x, a1.y, a1.z, a1.w};
      float wv[8] = {w0.x, w0.y, w0.z, w0.w, w1.x, w1.y, w1.z, w1.w};
      #pragma unroll
      for (int i = 0; i < 8; ++i)
        #pragma unroll
        for (int j = 0; j < 8; ++j) acc[i][j] += a[i] * wv[j];
    }
    __syncthreads();
  }

  // epilogue: write h, reduce attention scores across the 16 col-threads
  #pragma unroll
  for (int i = 0; i < 8; ++i) {
    int r = row0 + ty * 8 + i;
    bool ok = r < N;
    if (ok) {
      float4 o0 = make_float4(acc[i][0], acc[i][1], acc[i][2], acc[i][3]);
      float4 o1 = make_float4(acc[i][4], acc[i][5], acc[i][6], acc[i][7]);
      *(float4*)&H[(size_t)r * D + tx * 8] = o0;
      *(float4*)&H[(size_t)r * D + tx * 8 + 4] = o1;
    }
    float ps = 0.f, pd = 0.f;
    #pragma unroll
    for (int j = 0; j < 8; ++j) { ps += acc[i][j] * as_[j]; pd += acc[i][j] * ad_[j]; }
    ps += __shfl_down(ps, 8); pd += __shfl_down(pd, 8);
    ps += __shfl_down(ps, 4); pd += __shfl_down(pd, 4);
    ps += __shfl_down(ps, 2); pd += __shfl_down(pd, 2);
    ps += __shfl_down(ps, 1); pd += __shfl_down(pd, 1);
    if (ok && tx == 0) { Ss[r] = ps; Sd[r] = pd; }
  }
}

// ---------------- per-dst softmax + aggregate ----------------
// one wave per dst node; lanes cover 2 channels each.

__global__ __launch_bounds__(256) void agg_kernel(
    const float* __restrict__ H, const float* __restrict__ Ssrc, const float* __restrict__ Sdst,
    const int* __restrict__ off, const int* __restrict__ csr, const float* __restrict__ bias,
    float* __restrict__ out, int N, int do_relu)
{
  __shared__ float2 buf[4][64];
  int wid = threadIdx.x >> 6, lane = threadIdx.x & 63;
  int n = blockIdx.x * 4 + wid;
  if (n >= N) return;
  int st = off[n], en = off[n + 1];
  float sd = Sdst[n];

  // pass 1: segment max of leaky-relu'd logits
  float m = -1e30f;
  for (int j = st + lane; j < en; j += 64) {
    int s = csr[j];
    float e = Ssrc[s] + sd;
    e = e > 0.f ? e : NEG_SLOPE * e;
    m = fmaxf(m, e);
  }
  #pragma unroll
  for (int o = 32; o; o >>= 1) m = fmaxf(m, __shfl_xor(m, o));

  // pass 2: unnormalized exp weights + gather-accumulate
  float z = 0.f, ax = 0.f, ay = 0.f;
  int c = lane * 2;
  for (int base = st; base < en; base += 64) {
    int j = base + lane;
    int cnt = min(64, en - base);
    float p = 0.f; int s = 0;
    if (j < en) {
      s = csr[j];
      float e = Ssrc[s] + sd;
      e = e > 0.f ? e : NEG_SLOPE * e;
      p = __expf(e - m);
    }
    z += p;
    buf[wid][lane] = make_float2(p, __int_as_float(s));   // wave-synchronous
    for (int i = 0; i < cnt; ++i) {
      float2 ps = buf[wid][i];
      const float2 hv = *(const float2*)&H[(size_t)__float_as_int(ps.y) * D + c];
      ax += ps.x * hv.x;
      ay += ps.x * hv.y;
    }
  }
  #pragma unroll
  for (int o = 32; o; o >>= 1) z += __shfl_xor(z, o);
  float inv = 1.f / (z + 1e-16f);
  float2 bv = *(const float2*)&bias[c];
  ax = ax * inv + bv.x;
  ay = ay * inv + bv.y;
  if (do_relu) { ax = fmaxf(ax, 0.f); ay = fmaxf(ay, 0.f); }
  *(float2*)&out[(size_t)n * D + c] = make_float2(ax, ay);
}

// ---------------- launcher ----------------

extern "C" void kernel_launch(void* const* d_in, const int* in_sizes, int n_in,
                              void* d_out, int out_size, void* d_ws, size_t ws_size,
                              hipStream_t stream) {
  const float* x   = (const float*)d_in[0];
  const int*   ei  = (const int*)d_in[1];
  const float* W1  = (const float*)d_in[2];
  const float* as1 = (const float*)d_in[3];
  const float* ad1 = (const float*)d_in[4];
  const float* b1  = (const float*)d_in[5];
  const float* W2  = (const float*)d_in[6];
  const float* as2 = (const float*)d_in[7];
  const float* ad2 = (const float*)d_in[8];
  const float* b2  = (const float*)d_in[9];

  int N  = in_sizes[0] / D;
  int E  = in_sizes[1] / 2;
  int EP = E + N;
  const int* src = ei;
  const int* dst = ei + E;

  char* w = (char*)d_ws;
  auto alloc = [&](size_t bytes) -> char* {
    char* p = w; w += (bytes + 511) & ~(size_t)511; return p;
  };
  int*   deg  = (int*)alloc((size_t)N * 4);
  int*   cur  = (int*)alloc((size_t)N * 4);
  int*   off  = (int*)alloc(((size_t)N + 1) * 4);
  int*   csr  = (int*)alloc((size_t)EP * 4);
  float* ssrc = (float*)alloc((size_t)N * 4);
  float* sdst = (float*)alloc((size_t)N * 4);
  float* h    = (float*)alloc((size_t)N * D * 4);
  float* t1   = (float*)alloc((size_t)N * D * 4);

  hipMemsetAsync(deg, 0, (size_t)N * 4, stream);
  hipMemsetAsync(cur, 0, (size_t)N * 4, stream);

  int tpb = 256;
  hist_kernel<<<(EP + tpb - 1) / tpb, tpb, 0, stream>>>(dst, E, N, deg);
  scan_kernel<<<1, 1024, 0, stream>>>(deg, off, N);
  scatter_kernel<<<(EP + tpb - 1) / tpb, tpb, 0, stream>>>(src, dst, E, N, off, cur, csr);

  int nb = (N + 63) / 64;
  // layer 1
  gemm_fused<<<nb, 128, 0, stream>>>(x, W1, as1, ad1, h, ssrc, sdst, N);
  agg_kernel<<<(N + 3) / 4, 256, 0, stream>>>(h, ssrc, sdst, off, csr, b1, t1, N, 1);
  // layer 2
  gemm_fused<<<nb, 128, 0, stream>>>(t1, W2, as2, ad2, h, ssrc, sdst, N);
  agg_kernel<<<(N + 3) / 4, 256, 0, stream>>>(h, ssrc, sdst, off, csr, b2, (float*)d_out, N, 0);
}

// Round 2
// 371.630 us; speedup vs baseline: 1.1792x; 1.1792x over previous
//
#include <hip/hip_runtime.h>

#define D 128
#define NEG_SLOPE 0.2f

// ---------------- CSR build ----------------

__global__ void hist_kernel(const int* __restrict__ dst, int E, int N, int* __restrict__ deg) {
  int i = blockIdx.x * blockDim.x + threadIdx.x;
  if (i >= E + N) return;
  int d = (i < E) ? dst[i] : (i - E);
  atomicAdd(&deg[d], 1);
}

// stage 1: per-block (256-wide) sums of deg
__global__ __launch_bounds__(256) void partial_kernel(const int* __restrict__ deg,
                                                      int* __restrict__ psum, int N) {
  __shared__ int s[256];
  int t = threadIdx.x;
  int i = blockIdx.x * 256 + t;
  s[t] = (i < N) ? deg[i] : 0;
  __syncthreads();
  #pragma unroll
  for (int o = 128; o; o >>= 1) { if (t < o) s[t] += s[t + o]; __syncthreads(); }
  if (t == 0) psum[blockIdx.x] = s[0];
}

// stage 2: scan the (<=1024) block partials in one block; also writes off[N]=total
__global__ __launch_bounds__(1024) void scan_partials(const int* __restrict__ psum,
                                                      int* __restrict__ bbase,
                                                      int* __restrict__ off, int NB, int N) {
  __shared__ int s[1024];
  int t = threadIdx.x;
  int v = (t < NB) ? psum[t] : 0;
  s[t] = v;
  __syncthreads();
  for (int o = 1; o < 1024; o <<= 1) {
    int u = (t >= o) ? s[t - o] : 0;
    __syncthreads();
    s[t] += u;
    __syncthreads();
  }
  if (t < NB) bbase[t] = s[t] - v;      // exclusive base for block t
  if (t == 1023) off[N] = s[1023];      // grand total
}

// stage 3: per-block exclusive scan + base add -> final offsets
__global__ __launch_bounds__(256) void offs_kernel(const int* __restrict__ deg,
                                                   const int* __restrict__ bbase,
                                                   int* __restrict__ off, int N) {
  __shared__ int s[256];
  int t = threadIdx.x;
  int i = blockIdx.x * 256 + t;
  int v = (i < N) ? deg[i] : 0;
  s[t] = v;
  __syncthreads();
  #pragma unroll
  for (int o = 1; o < 256; o <<= 1) {
    int u = (t >= o) ? s[t - o] : 0;
    __syncthreads();
    s[t] += u;
    __syncthreads();
  }
  if (i < N) off[i] = bbase[blockIdx.x] + s[t] - v;
}

__global__ void scatter_kernel(const int* __restrict__ src, const int* __restrict__ dst,
                               int E, int N, const int* __restrict__ off,
                               int* __restrict__ cur, int* __restrict__ csr) {
  int i = blockIdx.x * blockDim.x + threadIdx.x;
  if (i >= E + N) return;
  int s, d;
  if (i < E) { s = src[i]; d = dst[i]; } else { s = i - E; d = s; }
  int pos = off[d] + atomicAdd(&cur[d], 1);
  csr[pos] = s;
}

// ---------------- fused GEMM + attention-score epilogue ----------------
// h = X @ W ; s_src = h @ a_src ; s_dst = h @ a_dst
// block = 128 threads (2 waves), tile = 64 rows x 128 cols, K in 2 chunks of 64.
// A staged TRANSPOSED in LDS (At[k][m], stride 68 -> conflict-free b128 reads).

__global__ __launch_bounds__(128) void gemm_fused(
    const float* __restrict__ X, const float* __restrict__ W,
    const float* __restrict__ avs, const float* __restrict__ avd,
    float* __restrict__ H, float* __restrict__ Ss, float* __restrict__ Sd, int N)
{
  __shared__ float At[64 * 68];   // [k2][m]
  __shared__ float Ws[64 * 128];  // [k2][n]
  int tid = threadIdx.x;
  int tx = tid & 15, ty = tid >> 4;     // tx: col group (16), ty: row group (8)
  int row0 = blockIdx.x * 64;

  float acc[8][8];
  #pragma unroll
  for (int i = 0; i < 8; ++i)
    #pragma unroll
    for (int j = 0; j < 8; ++j) acc[i][j] = 0.f;

  float as_[8], ad_[8];
  #pragma unroll
  for (int j = 0; j < 8; ++j) { as_[j] = avs[tx * 8 + j]; ad_[j] = avd[tx * 8 + j]; }

  for (int kc = 0; kc < 2; ++kc) {
    // stage A chunk transposed: 64 rows x 64 k
    #pragma unroll
    for (int it = 0; it < 16; ++it) {
      int lin = it * 128 + tid;        // float2 index, 0..2047
      int r = lin >> 5;                // 0..63
      int c2 = lin & 31;               // k pair
      int gr = row0 + r;
      float2 v = make_float2(0.f, 0.f);
      if (gr < N) v = *(const float2*)&X[(size_t)gr * D + kc * 64 + c2 * 2];
      At[(c2 * 2) * 68 + r] = v.x;
      At[(c2 * 2 + 1) * 68 + r] = v.y;
    }
    // stage W chunk: 64 k x 128 n
    #pragma unroll
    for (int it = 0; it < 16; ++it) {
      int lin = it * 128 + tid;        // float4 index, 0..2047
      int r = lin >> 5;                // 0..63 (k)
      int c4 = lin & 31;
      *(float4*)&Ws[r * 128 + c4 * 4] =
          *(const float4*)&W[(size_t)(kc * 64 + r) * D + c4 * 4];
    }
    __syncthreads();
    #pragma unroll 4
    for (int k = 0; k < 64; ++k) {
      float4 a0 = *(const float4*)&At[k * 68 + ty * 8];
      float4 a1 = *(const float4*)&At[k * 68 + ty * 8 + 4];
      float4 w0 = *(const float4*)&Ws[k * 128 + tx * 8];
      float4 w1 = *(const float4*)&Ws[k * 128 + tx * 8 + 4];
      float a[8] = {a0.x, a0.y, a0.z, a0.w, a1.x, a1.y, a1.z, a1.w};
      float wv[8] = {w0.x, w0.y, w0.z, w0.w, w1.x, w1.y, w1.z, w1.w};
      #pragma unroll
      for (int i = 0; i < 8; ++i)
        #pragma unroll
        for (int j = 0; j < 8; ++j) acc[i][j] += a[i] * wv[j];
    }
    __syncthreads();
  }

  // epilogue: write h, reduce attention scores across the 16 col-threads
  #pragma unroll
  for (int i = 0; i < 8; ++i) {
    int r = row0 + ty * 8 + i;
    bool ok = r < N;
    if (ok) {
      float4 o0 = make_float4(acc[i][0], acc[i][1], acc[i][2], acc[i][3]);
      float4 o1 = make_float4(acc[i][4], acc[i][5], acc[i][6], acc[i][7]);
      *(float4*)&H[(size_t)r * D + tx * 8] = o0;
      *(float4*)&H[(size_t)r * D + tx * 8 + 4] = o1;
    }
    float ps = 0.f, pd = 0.f;
    #pragma unroll
    for (int j = 0; j < 8; ++j) { ps += acc[i][j] * as_[j]; pd += acc[i][j] * ad_[j]; }
    ps += __shfl_down(ps, 8); pd += __shfl_down(pd, 8);
    ps += __shfl_down(ps, 4); pd += __shfl_down(pd, 4);
    ps += __shfl_down(ps, 2); pd += __shfl_down(pd, 2);
    ps += __shfl_down(ps, 1); pd += __shfl_down(pd, 1);
    if (ok && tx == 0) { Ss[r] = ps; Sd[r] = pd; }
  }
}

// ---------------- per-dst softmax + aggregate ----------------
// one wave per dst node; lanes cover 2 channels each.

__global__ __launch_bounds__(256) void agg_kernel(
    const float* __restrict__ H, const float* __restrict__ Ssrc, const float* __restrict__ Sdst,
    const int* __restrict__ off, const int* __restrict__ csr, const float* __restrict__ bias,
    float* __restrict__ out, int N, int do_relu)
{
  __shared__ float2 buf[4][64];
  int wid = threadIdx.x >> 6, lane = threadIdx.x & 63;
  int n = blockIdx.x * 4 + wid;
  if (n >= N) return;
  int st = off[n], en = off[n + 1];
  float sd = Sdst[n];

  // pass 1: segment max of leaky-relu'd logits
  float m = -1e30f;
  for (int j = st + lane; j < en; j += 64) {
    int s = csr[j];
    float e = Ssrc[s] + sd;
    e = e > 0.f ? e : NEG_SLOPE * e;
    m = fmaxf(m, e);
  }
  #pragma unroll
  for (int o = 32; o; o >>= 1) m = fmaxf(m, __shfl_xor(m, o));

  // pass 2: unnormalized exp weights + gather-accumulate
  float z = 0.f, ax = 0.f, ay = 0.f;
  int c = lane * 2;
  for (int base = st; base < en; base += 64) {
    int j = base + lane;
    int cnt = min(64, en - base);
    float p = 0.f; int s = 0;
    if (j < en) {
      s = csr[j];
      float e = Ssrc[s] + sd;
      e = e > 0.f ? e : NEG_SLOPE * e;
      p = __expf(e - m);
    }
    z += p;
    buf[wid][lane] = make_float2(p, __int_as_float(s));   // wave-synchronous
    for (int i = 0; i < cnt; ++i) {
      float2 ps = buf[wid][i];
      const float2 hv = *(const float2*)&H[(size_t)__float_as_int(ps.y) * D + c];
      ax += ps.x * hv.x;
      ay += ps.x * hv.y;
    }
  }
  #pragma unroll
  for (int o = 32; o; o >>= 1) z += __shfl_xor(z, o);
  float inv = 1.f / (z + 1e-16f);
  float2 bv = *(const float2*)&bias[c];
  ax = ax * inv + bv.x;
  ay = ay * inv + bv.y;
  if (do_relu) { ax = fmaxf(ax, 0.f); ay = fmaxf(ay, 0.f); }
  *(float2*)&out[(size_t)n * D + c] = make_float2(ax, ay);
}

// ---------------- launcher ----------------

extern "C" void kernel_launch(void* const* d_in, const int* in_sizes, int n_in,
                              void* d_out, int out_size, void* d_ws, size_t ws_size,
                              hipStream_t stream) {
  const float* x   = (const float*)d_in[0];
  const int*   ei  = (const int*)d_in[1];
  const float* W1  = (const float*)d_in[2];
  const float* as1 = (const float*)d_in[3];
  const float* ad1 = (const float*)d_in[4];
  const float* b1  = (const float*)d_in[5];
  const float* W2  = (const float*)d_in[6];
  const float* as2 = (const float*)d_in[7];
  const float* ad2 = (const float*)d_in[8];
  const float* b2  = (const float*)d_in[9];

  int N  = in_sizes[0] / D;
  int E  = in_sizes[1] / 2;
  int EP = E + N;
  const int* src = ei;
  const int* dst = ei + E;

  char* w = (char*)d_ws;
  auto alloc = [&](size_t bytes) -> char* {
    char* p = w; w += (bytes + 511) & ~(size_t)511; return p;
  };
  int NB = (N + 255) / 256;           // blocks for the scan stages (196)
  int*   deg   = (int*)alloc((size_t)N * 4);
  int*   cur   = (int*)alloc((size_t)N * 4);
  int*   off   = (int*)alloc(((size_t)N + 1) * 4);
  int*   csr   = (int*)alloc((size_t)EP * 4);
  int*   psum  = (int*)alloc((size_t)NB * 4);
  int*   bbase = (int*)alloc((size_t)NB * 4);
  float* ssrc  = (float*)alloc((size_t)N * 4);
  float* sdst  = (float*)alloc((size_t)N * 4);
  float* h     = (float*)alloc((size_t)N * D * 4);
  float* t1    = (float*)alloc((size_t)N * D * 4);

  hipMemsetAsync(deg, 0, (size_t)N * 4, stream);
  hipMemsetAsync(cur, 0, (size_t)N * 4, stream);

  int tpb = 256;
  hist_kernel<<<(EP + tpb - 1) / tpb, tpb, 0, stream>>>(dst, E, N, deg);
  partial_kernel<<<NB, 256, 0, stream>>>(deg, psum, N);
  scan_partials<<<1, 1024, 0, stream>>>(psum, bbase, off, NB, N);
  offs_kernel<<<NB, 256, 0, stream>>>(deg, bbase, off, N);
  scatter_kernel<<<(EP + tpb - 1) / tpb, tpb, 0, stream>>>(src, dst, E, N, off, cur, csr);

  int nb = (N + 63) / 64;
  // layer 1
  gemm_fused<<<nb, 128, 0, stream>>>(x, W1, as1, ad1, h, ssrc, sdst, N);
  agg_kernel<<<(N + 3) / 4, 256, 0, stream>>>(h, ssrc, sdst, off, csr, b1, t1, N, 1);
  // layer 2
  gemm_fused<<<nb, 128, 0, stream>>>(t1, W2, as2, ad2, h, ssrc, sdst, N);
  agg_kernel<<<(N + 3) / 4, 256, 0, stream>>>(h, ssrc, sdst, off, csr, b2, (float*)d_out, N, 0);
}

// Round 3
// 357.411 us; speedup vs baseline: 1.2261x; 1.0398x over previous
//
#include <hip/hip_runtime.h>

#define D 128
#define NEG_SLOPE 0.2f

// ---------------- CSR build ----------------

__global__ void hist_kernel(const int* __restrict__ dst, int E, int N, int* __restrict__ deg) {
  int i = blockIdx.x * blockDim.x + threadIdx.x;
  if (i >= E + N) return;
  int d = (i < E) ? dst[i] : (i - E);
  atomicAdd(&deg[d], 1);
}

// stage 1: per-block (256-wide) sums of deg
__global__ __launch_bounds__(256) void partial_kernel(const int* __restrict__ deg,
                                                      int* __restrict__ psum, int N) {
  __shared__ int s[256];
  int t = threadIdx.x;
  int i = blockIdx.x * 256 + t;
  s[t] = (i < N) ? deg[i] : 0;
  __syncthreads();
  #pragma unroll
  for (int o = 128; o; o >>= 1) { if (t < o) s[t] += s[t + o]; __syncthreads(); }
  if (t == 0) psum[blockIdx.x] = s[0];
}

// stage 2: scan the (<=1024) block partials in one block; also writes off[N]=total
__global__ __launch_bounds__(1024) void scan_partials(const int* __restrict__ psum,
                                                      int* __restrict__ bbase,
                                                      int* __restrict__ off, int NB, int N) {
  __shared__ int s[1024];
  int t = threadIdx.x;
  int v = (t < NB) ? psum[t] : 0;
  s[t] = v;
  __syncthreads();
  for (int o = 1; o < 1024; o <<= 1) {
    int u = (t >= o) ? s[t - o] : 0;
    __syncthreads();
    s[t] += u;
    __syncthreads();
  }
  if (t < NB) bbase[t] = s[t] - v;      // exclusive base for block t
  if (t == 1023) off[N] = s[1023];      // grand total
}

// stage 3: per-block exclusive scan + base add -> final offsets
__global__ __launch_bounds__(256) void offs_kernel(const int* __restrict__ deg,
                                                   const int* __restrict__ bbase,
                                                   int* __restrict__ off, int N) {
  __shared__ int s[256];
  int t = threadIdx.x;
  int i = blockIdx.x * 256 + t;
  int v = (i < N) ? deg[i] : 0;
  s[t] = v;
  __syncthreads();
  #pragma unroll
  for (int o = 1; o < 256; o <<= 1) {
    int u = (t >= o) ? s[t - o] : 0;
    __syncthreads();
    s[t] += u;
    __syncthreads();
  }
  if (i < N) off[i] = bbase[blockIdx.x] + s[t] - v;
}

__global__ void scatter_kernel(const int* __restrict__ src, const int* __restrict__ dst,
                               int E, int N, const int* __restrict__ off,
                               int* __restrict__ cur, int* __restrict__ csr) {
  int i = blockIdx.x * blockDim.x + threadIdx.x;
  if (i >= E + N) return;
  int s, d;
  if (i < E) { s = src[i]; d = dst[i]; } else { s = i - E; d = s; }
  int pos = off[d] + atomicAdd(&cur[d], 1);
  csr[pos] = s;
}

// ---------------- fused GEMM + attention-score epilogue ----------------
// h = X @ W ; s_src = h @ a_src ; s_dst = h @ a_dst
// block = 128 threads (2 waves), tile = 64 rows x 128 cols, K in 4 chunks of 32.
// LDS 25.1 KB -> 6 blocks/CU (12 waves/CU).  Micro-tile is COLUMN-SPLIT
// (cols tx*4 and 64+tx*4) and ROW-SPLIT (rows ty*4 and 32+ty*4) so that both
// Ws and At inner-loop float4 reads are bank-conflict-free (16B-contiguous
// across lanes -> only free 2-way aliasing).

__global__ __launch_bounds__(128, 3) void gemm_fused(
    const float* __restrict__ X, const float* __restrict__ W,
    const float* __restrict__ avs, const float* __restrict__ avd,
    float* __restrict__ H, float* __restrict__ Ss, float* __restrict__ Sd, int N)
{
  __shared__ float At[32 * 68];   // [k][m], stride 68
  __shared__ float Ws[32 * 128];  // [k][n]
  int tid = threadIdx.x;
  int tx = tid & 15, ty = tid >> 4;     // tx: col group (16), ty: row group (8)
  int row0 = blockIdx.x * 64;

  float acc[8][8];
  #pragma unroll
  for (int i = 0; i < 8; ++i)
    #pragma unroll
    for (int j = 0; j < 8; ++j) acc[i][j] = 0.f;

  float as_[8], ad_[8];
  #pragma unroll
  for (int j = 0; j < 4; ++j) {
    as_[j]     = avs[tx * 4 + j];      ad_[j]     = avd[tx * 4 + j];
    as_[j + 4] = avs[64 + tx * 4 + j]; ad_[j + 4] = avd[64 + tx * 4 + j];
  }

  for (int kc = 0; kc < 4; ++kc) {
    // stage A chunk transposed: 64 rows x 32 k  (1024 float2)
    #pragma unroll
    for (int it = 0; it < 8; ++it) {
      int lin = it * 128 + tid;        // float2 index, 0..1023
      int r = lin >> 4;                // row 0..63
      int c2 = lin & 15;               // k pair 0..15
      int gr = row0 + r;
      float2 v = make_float2(0.f, 0.f);
      if (gr < N) v = *(const float2*)&X[(size_t)gr * D + kc * 32 + c2 * 2];
      At[(c2 * 2) * 68 + r] = v.x;
      At[(c2 * 2 + 1) * 68 + r] = v.y;
    }
    // stage W chunk: 32 k x 128 n  (1024 float4, fully contiguous)
    #pragma unroll
    for (int it = 0; it < 8; ++it) {
      int lin = it * 128 + tid;        // float4 index, 0..1023
      int r = lin >> 5;                // k 0..31
      int c4 = lin & 31;
      *(float4*)&Ws[r * 128 + c4 * 4] =
          *(const float4*)&W[(size_t)(kc * 32 + r) * D + c4 * 4];
    }
    __syncthreads();
    #pragma unroll 8
    for (int k = 0; k < 32; ++k) {
      float4 a0 = *(const float4*)&At[k * 68 + ty * 4];        // rows ty*4..+3
      float4 a1 = *(const float4*)&At[k * 68 + 32 + ty * 4];   // rows 32+ty*4..+3
      float4 w0 = *(const float4*)&Ws[k * 128 + tx * 4];       // cols tx*4..+3
      float4 w1 = *(const float4*)&Ws[k * 128 + 64 + tx * 4];  // cols 64+tx*4..+3
      float a[8] = {a0.x, a0.y, a0.z, a0.w, a1.x, a1.y, a1.z, a1.w};
      float wv[8] = {w0.x, w0.y, w0.z, w0.w, w1.x, w1.y, w1.z, w1.w};
      #pragma unroll
      for (int i = 0; i < 8; ++i)
        #pragma unroll
        for (int j = 0; j < 8; ++j) acc[i][j] += a[i] * wv[j];
    }
    __syncthreads();
  }

  // epilogue: write h, reduce attention scores across the 16 col-threads
  #pragma unroll
  for (int i = 0; i < 8; ++i) {
    int r = row0 + ((i < 4) ? (ty * 4 + i) : (32 + ty * 4 + (i - 4)));
    bool ok = r < N;
    if (ok) {
      float4 o0 = make_float4(acc[i][0], acc[i][1], acc[i][2], acc[i][3]);
      float4 o1 = make_float4(acc[i][4], acc[i][5], acc[i][6], acc[i][7]);
      *(float4*)&H[(size_t)r * D + tx * 4] = o0;
      *(float4*)&H[(size_t)r * D + 64 + tx * 4] = o1;
    }
    float ps = 0.f, pd = 0.f;
    #pragma unroll
    for (int j = 0; j < 8; ++j) { ps += acc[i][j] * as_[j]; pd += acc[i][j] * ad_[j]; }
    ps += __shfl_down(ps, 8); pd += __shfl_down(pd, 8);
    ps += __shfl_down(ps, 4); pd += __shfl_down(pd, 4);
    ps += __shfl_down(ps, 2); pd += __shfl_down(pd, 2);
    ps += __shfl_down(ps, 1); pd += __shfl_down(pd, 1);
    if (ok && tx == 0) { Ss[r] = ps; Sd[r] = pd; }
  }
}

// ---------------- per-dst softmax + aggregate ----------------
// one wave per dst node; lanes cover 2 channels each.

__global__ __launch_bounds__(256) void agg_kernel(
    const float* __restrict__ H, const float* __restrict__ Ssrc, const float* __restrict__ Sdst,
    const int* __restrict__ off, const int* __restrict__ csr, const float* __restrict__ bias,
    float* __restrict__ out, int N, int do_relu)
{
  __shared__ float2 buf[4][64];
  int wid = threadIdx.x >> 6, lane = threadIdx.x & 63;
  int n = blockIdx.x * 4 + wid;
  if (n >= N) return;
  int st = off[n], en = off[n + 1];
  float sd = Sdst[n];

  // pass 1: segment max of leaky-relu'd logits
  float m = -1e30f;
  for (int j = st + lane; j < en; j += 64) {
    int s = csr[j];
    float e = Ssrc[s] + sd;
    e = e > 0.f ? e : NEG_SLOPE * e;
    m = fmaxf(m, e);
  }
  #pragma unroll
  for (int o = 32; o; o >>= 1) m = fmaxf(m, __shfl_xor(m, o));

  // pass 2: unnormalized exp weights + gather-accumulate
  float z = 0.f, ax = 0.f, ay = 0.f;
  int c = lane * 2;
  for (int base = st; base < en; base += 64) {
    int j = base + lane;
    int cnt = min(64, en - base);
    float p = 0.f; int s = 0;
    if (j < en) {
      s = csr[j];
      float e = Ssrc[s] + sd;
      e = e > 0.f ? e : NEG_SLOPE * e;
      p = __expf(e - m);
    }
    z += p;
    buf[wid][lane] = make_float2(p, __int_as_float(s));   // wave-synchronous
    for (int i = 0; i < cnt; ++i) {
      float2 ps = buf[wid][i];
      const float2 hv = *(const float2*)&H[(size_t)__float_as_int(ps.y) * D + c];
      ax += ps.x * hv.x;
      ay += ps.x * hv.y;
    }
  }
  #pragma unroll
  for (int o = 32; o; o >>= 1) z += __shfl_xor(z, o);
  float inv = 1.f / (z + 1e-16f);
  float2 bv = *(const float2*)&bias[c];
  ax = ax * inv + bv.x;
  ay = ay * inv + bv.y;
  if (do_relu) { ax = fmaxf(ax, 0.f); ay = fmaxf(ay, 0.f); }
  *(float2*)&out[(size_t)n * D + c] = make_float2(ax, ay);
}

// ---------------- launcher ----------------

extern "C" void kernel_launch(void* const* d_in, const int* in_sizes, int n_in,
                              void* d_out, int out_size, void* d_ws, size_t ws_size,
                              hipStream_t stream) {
  const float* x   = (const float*)d_in[0];
  const int*   ei  = (const int*)d_in[1];
  const float* W1  = (const float*)d_in[2];
  const float* as1 = (const float*)d_in[3];
  const float* ad1 = (const float*)d_in[4];
  const float* b1  = (const float*)d_in[5];
  const float* W2  = (const float*)d_in[6];
  const float* as2 = (const float*)d_in[7];
  const float* ad2 = (const float*)d_in[8];
  const float* b2  = (const float*)d_in[9];

  int N  = in_sizes[0] / D;
  int E  = in_sizes[1] / 2;
  int EP = E + N;
  const int* src = ei;
  const int* dst = ei + E;

  char* w = (char*)d_ws;
  auto alloc = [&](size_t bytes) -> char* {
    char* p = w; w += (bytes + 511) & ~(size_t)511; return p;
  };
  int NB = (N + 255) / 256;           // blocks for the scan stages (196)
  int*   deg   = (int*)alloc((size_t)N * 4);
  int*   cur   = (int*)alloc((size_t)N * 4);
  int*   off   = (int*)alloc(((size_t)N + 1) * 4);
  int*   csr   = (int*)alloc((size_t)EP * 4);
  int*   psum  = (int*)alloc((size_t)NB * 4);
  int*   bbase = (int*)alloc((size_t)NB * 4);
  float* ssrc  = (float*)alloc((size_t)N * 4);
  float* sdst  = (float*)alloc((size_t)N * 4);
  float* h     = (float*)alloc((size_t)N * D * 4);
  float* t1    = (float*)alloc((size_t)N * D * 4);

  hipMemsetAsync(deg, 0, (size_t)N * 4, stream);
  hipMemsetAsync(cur, 0, (size_t)N * 4, stream);

  int tpb = 256;
  hist_kernel<<<(EP + tpb - 1) / tpb, tpb, 0, stream>>>(dst, E, N, deg);
  partial_kernel<<<NB, 256, 0, stream>>>(deg, psum, N);
  scan_partials<<<1, 1024, 0, stream>>>(psum, bbase, off, NB, N);
  offs_kernel<<<NB, 256, 0, stream>>>(deg, bbase, off, N);
  scatter_kernel<<<(EP + tpb - 1) / tpb, tpb, 0, stream>>>(src, dst, E, N, off, cur, csr);

  int nb = (N + 63) / 64;
  // layer 1
  gemm_fused<<<nb, 128, 0, stream>>>(x, W1, as1, ad1, h, ssrc, sdst, N);
  agg_kernel<<<(N + 3) / 4, 256, 0, stream>>>(h, ssrc, sdst, off, csr, b1, t1, N, 1);
  // layer 2
  gemm_fused<<<nb, 128, 0, stream>>>(t1, W2, as2, ad2, h, ssrc, sdst, N);
  agg_kernel<<<(N + 3) / 4, 256, 0, stream>>>(h, ssrc, sdst, off, csr, b2, (float*)d_out, N, 0);
}

// Round 4
// 342.690 us; speedup vs baseline: 1.2788x; 1.0430x over previous
//
#include <hip/hip_runtime.h>

#define D 128
#define NEG_SLOPE 0.2f

// ---------------- CSR build ----------------

__global__ void hist_kernel(const int* __restrict__ dst, int E, int N, int* __restrict__ deg) {
  int i = blockIdx.x * blockDim.x + threadIdx.x;
  if (i >= E + N) return;
  int d = (i < E) ? dst[i] : (i - E);
  atomicAdd(&deg[d], 1);
}

// stage 1: per-block (256-wide) sums of deg
__global__ __launch_bounds__(256) void partial_kernel(const int* __restrict__ deg,
                                                      int* __restrict__ psum, int N) {
  __shared__ int s[256];
  int t = threadIdx.x;
  int i = blockIdx.x * 256 + t;
  s[t] = (i < N) ? deg[i] : 0;
  __syncthreads();
  #pragma unroll
  for (int o = 128; o; o >>= 1) { if (t < o) s[t] += s[t + o]; __syncthreads(); }
  if (t == 0) psum[blockIdx.x] = s[0];
}

// stage 2: scan the (<=1024) block partials in one block; also writes off[N]=total
__global__ __launch_bounds__(1024) void scan_partials(const int* __restrict__ psum,
                                                      int* __restrict__ bbase,
                                                      int* __restrict__ off, int NB, int N) {
  __shared__ int s[1024];
  int t = threadIdx.x;
  int v = (t < NB) ? psum[t] : 0;
  s[t] = v;
  __syncthreads();
  for (int o = 1; o < 1024; o <<= 1) {
    int u = (t >= o) ? s[t - o] : 0;
    __syncthreads();
    s[t] += u;
    __syncthreads();
  }
  if (t < NB) bbase[t] = s[t] - v;      // exclusive base for block t
  if (t == 1023) off[N] = s[1023];      // grand total
}

// stage 3: per-block exclusive scan + base add -> final offsets
__global__ __launch_bounds__(256) void offs_kernel(const int* __restrict__ deg,
                                                   const int* __restrict__ bbase,
                                                   int* __restrict__ off, int N) {
  __shared__ int s[256];
  int t = threadIdx.x;
  int i = blockIdx.x * 256 + t;
  int v = (i < N) ? deg[i] : 0;
  s[t] = v;
  __syncthreads();
  #pragma unroll
  for (int o = 1; o < 256; o <<= 1) {
    int u = (t >= o) ? s[t - o] : 0;
    __syncthreads();
    s[t] += u;
    __syncthreads();
  }
  if (i < N) off[i] = bbase[blockIdx.x] + s[t] - v;
}

__global__ void scatter_kernel(const int* __restrict__ src, const int* __restrict__ dst,
                               int E, int N, const int* __restrict__ off,
                               int* __restrict__ cur, int* __restrict__ csr) {
  int i = blockIdx.x * blockDim.x + threadIdx.x;
  if (i >= E + N) return;
  int s, d;
  if (i < E) { s = src[i]; d = dst[i]; } else { s = i - E; d = s; }
  int pos = off[d] + atomicAdd(&cur[d], 1);
  csr[pos] = s;
}

// ---------------- fused GEMM + attention-score epilogue ----------------
// h = X @ W ; s_src = h @ a_src ; s_dst = h @ a_dst
// block = 128 threads (2 waves), tile = 64 rows x 128 cols, K in 4 chunks of 32.
// LDS 25.1 KB -> 6 blocks/CU (12 waves/CU).  Micro-tile is COLUMN-SPLIT
// (cols tx*4 and 64+tx*4) and ROW-SPLIT (rows ty*4 and 32+ty*4) so that both
// Ws and At inner-loop float4 reads are bank-conflict-free.

__global__ __launch_bounds__(128, 3) void gemm_fused(
    const float* __restrict__ X, const float* __restrict__ W,
    const float* __restrict__ avs, const float* __restrict__ avd,
    float* __restrict__ H, float* __restrict__ Ss, float* __restrict__ Sd, int N)
{
  __shared__ float At[32 * 68];   // [k][m], stride 68
  __shared__ float Ws[32 * 128];  // [k][n]
  int tid = threadIdx.x;
  int tx = tid & 15, ty = tid >> 4;     // tx: col group (16), ty: row group (8)
  int row0 = blockIdx.x * 64;

  float acc[8][8];
  #pragma unroll
  for (int i = 0; i < 8; ++i)
    #pragma unroll
    for (int j = 0; j < 8; ++j) acc[i][j] = 0.f;

  float as_[8], ad_[8];
  #pragma unroll
  for (int j = 0; j < 4; ++j) {
    as_[j]     = avs[tx * 4 + j];      ad_[j]     = avd[tx * 4 + j];
    as_[j + 4] = avs[64 + tx * 4 + j]; ad_[j + 4] = avd[64 + tx * 4 + j];
  }

  for (int kc = 0; kc < 4; ++kc) {
    // stage A chunk transposed: 64 rows x 32 k  (1024 float2)
    #pragma unroll
    for (int it = 0; it < 8; ++it) {
      int lin = it * 128 + tid;        // float2 index, 0..1023
      int r = lin >> 4;                // row 0..63
      int c2 = lin & 15;               // k pair 0..15
      int gr = row0 + r;
      float2 v = make_float2(0.f, 0.f);
      if (gr < N) v = *(const float2*)&X[(size_t)gr * D + kc * 32 + c2 * 2];
      At[(c2 * 2) * 68 + r] = v.x;
      At[(c2 * 2 + 1) * 68 + r] = v.y;
    }
    // stage W chunk: 32 k x 128 n  (1024 float4, fully contiguous)
    #pragma unroll
    for (int it = 0; it < 8; ++it) {
      int lin = it * 128 + tid;        // float4 index, 0..1023
      int r = lin >> 5;                // k 0..31
      int c4 = lin & 31;
      *(float4*)&Ws[r * 128 + c4 * 4] =
          *(const float4*)&W[(size_t)(kc * 32 + r) * D + c4 * 4];
    }
    __syncthreads();
    #pragma unroll 8
    for (int k = 0; k < 32; ++k) {
      float4 a0 = *(const float4*)&At[k * 68 + ty * 4];        // rows ty*4..+3
      float4 a1 = *(const float4*)&At[k * 68 + 32 + ty * 4];   // rows 32+ty*4..+3
      float4 w0 = *(const float4*)&Ws[k * 128 + tx * 4];       // cols tx*4..+3
      float4 w1 = *(const float4*)&Ws[k * 128 + 64 + tx * 4];  // cols 64+tx*4..+3
      float a[8] = {a0.x, a0.y, a0.z, a0.w, a1.x, a1.y, a1.z, a1.w};
      float wv[8] = {w0.x, w0.y, w0.z, w0.w, w1.x, w1.y, w1.z, w1.w};
      #pragma unroll
      for (int i = 0; i < 8; ++i)
        #pragma unroll
        for (int j = 0; j < 8; ++j) acc[i][j] += a[i] * wv[j];
    }
    __syncthreads();
  }

  // epilogue: write h, reduce attention scores across the 16 col-threads
  #pragma unroll
  for (int i = 0; i < 8; ++i) {
    int r = row0 + ((i < 4) ? (ty * 4 + i) : (32 + ty * 4 + (i - 4)));
    bool ok = r < N;
    if (ok) {
      float4 o0 = make_float4(acc[i][0], acc[i][1], acc[i][2], acc[i][3]);
      float4 o1 = make_float4(acc[i][4], acc[i][5], acc[i][6], acc[i][7]);
      *(float4*)&H[(size_t)r * D + tx * 4] = o0;
      *(float4*)&H[(size_t)r * D + 64 + tx * 4] = o1;
    }
    float ps = 0.f, pd = 0.f;
    #pragma unroll
    for (int j = 0; j < 8; ++j) { ps += acc[i][j] * as_[j]; pd += acc[i][j] * ad_[j]; }
    ps += __shfl_down(ps, 8); pd += __shfl_down(pd, 8);
    ps += __shfl_down(ps, 4); pd += __shfl_down(pd, 4);
    ps += __shfl_down(ps, 2); pd += __shfl_down(pd, 2);
    ps += __shfl_down(ps, 1); pd += __shfl_down(pd, 1);
    if (ok && tx == 0) { Ss[r] = ps; Sd[r] = pd; }
  }
}

// ---------------- per-dst softmax + aggregate ----------------
// one wave per dst node; lanes cover 2 channels each.
// Gather loop: (p,s) broadcast via __shfl with wave-uniform index (v_readlane),
// unrolled x8 with gather/FMA split so 8 loads are in flight -> breaks the
// LDS->vmem->FMA serial chain that made R3's version latency-bound.

__global__ __launch_bounds__(256) void agg_kernel(
    const float* __restrict__ H, const float* __restrict__ Ssrc, const float* __restrict__ Sdst,
    const int* __restrict__ off, const int* __restrict__ csr, const float* __restrict__ bias,
    float* __restrict__ out, int N, int do_relu)
{
  int wid = threadIdx.x >> 6, lane = threadIdx.x & 63;
  int n = blockIdx.x * 4 + wid;
  if (n >= N) return;
  int st = off[n], en = off[n + 1];
  float sd = Sdst[n];

  // pass 1: segment max of leaky-relu'd logits
  float m = -1e30f;
  for (int j = st + lane; j < en; j += 64) {
    int s = csr[j];
    float e = Ssrc[s] + sd;
    e = e > 0.f ? e : NEG_SLOPE * e;
    m = fmaxf(m, e);
  }
  #pragma unroll
  for (int o = 32; o; o >>= 1) m = fmaxf(m, __shfl_xor(m, o));

  // pass 2: unnormalized exp weights + gather-accumulate
  float z = 0.f, ax = 0.f, ay = 0.f;
  int c = lane * 2;
  for (int base = st; base < en; base += 64) {
    int j = base + lane;
    int cnt = min(64, en - base);        // >=1 (self-loops)
    float p = 0.f; int s = 0;
    if (j < en) {
      s = csr[j];
      float e = Ssrc[s] + sd;
      e = e > 0.f ? e : NEG_SLOPE * e;
      p = __expf(e - m);
    }
    z += p;
    for (int i = 0; i < cnt; i += 8) {
      float pu[8]; float2 hv[8];
      #pragma unroll
      for (int u = 0; u < 8; ++u) {
        int idx = i + u;
        int iu = idx < cnt ? idx : cnt - 1;     // uniform clamp, no divergence
        float pb = __shfl(p, iu);               // v_readlane (uniform idx)
        int   sb = __shfl(s, iu);
        pu[u] = idx < cnt ? pb : 0.f;
        hv[u] = *(const float2*)&H[(size_t)sb * D + c];
      }
      #pragma unroll
      for (int u = 0; u < 8; ++u) { ax += pu[u] * hv[u].x; ay += pu[u] * hv[u].y; }
    }
  }
  #pragma unroll
  for (int o = 32; o; o >>= 1) z += __shfl_xor(z, o);
  float inv = 1.f / (z + 1e-16f);
  float2 bv = *(const float2*)&bias[c];
  ax = ax * inv + bv.x;
  ay = ay * inv + bv.y;
  if (do_relu) { ax = fmaxf(ax, 0.f); ay = fmaxf(ay, 0.f); }
  *(float2*)&out[(size_t)n * D + c] = make_float2(ax, ay);
}

// ---------------- launcher ----------------

extern "C" void kernel_launch(void* const* d_in, const int* in_sizes, int n_in,
                              void* d_out, int out_size, void* d_ws, size_t ws_size,
                              hipStream_t stream) {
  const float* x   = (const float*)d_in[0];
  const int*   ei  = (const int*)d_in[1];
  const float* W1  = (const float*)d_in[2];
  const float* as1 = (const float*)d_in[3];
  const float* ad1 = (const float*)d_in[4];
  const float* b1  = (const float*)d_in[5];
  const float* W2  = (const float*)d_in[6];
  const float* as2 = (const float*)d_in[7];
  const float* ad2 = (const float*)d_in[8];
  const float* b2  = (const float*)d_in[9];

  int N  = in_sizes[0] / D;
  int E  = in_sizes[1] / 2;
  int EP = E + N;
  const int* src = ei;
  const int* dst = ei + E;

  char* w = (char*)d_ws;
  auto alloc = [&](size_t bytes) -> char* {
    char* p = w; w += (bytes + 511) & ~(size_t)511; return p;
  };
  int NB = (N + 255) / 256;           // blocks for the scan stages (196)
  int*   deg   = (int*)alloc((size_t)N * 4);
  int*   cur   = (int*)alloc((size_t)N * 4);
  int*   off   = (int*)alloc(((size_t)N + 1) * 4);
  int*   csr   = (int*)alloc((size_t)EP * 4);
  int*   psum  = (int*)alloc((size_t)NB * 4);
  int*   bbase = (int*)alloc((size_t)NB * 4);
  float* ssrc  = (float*)alloc((size_t)N * 4);
  float* sdst  = (float*)alloc((size_t)N * 4);
  float* h     = (float*)alloc((size_t)N * D * 4);
  float* t1    = (float*)alloc((size_t)N * D * 4);

  hipMemsetAsync(deg, 0, (size_t)N * 4, stream);
  hipMemsetAsync(cur, 0, (size_t)N * 4, stream);

  int tpb = 256;
  hist_kernel<<<(EP + tpb - 1) / tpb, tpb, 0, stream>>>(dst, E, N, deg);
  partial_kernel<<<NB, 256, 0, stream>>>(deg, psum, N);
  scan_partials<<<1, 1024, 0, stream>>>(psum, bbase, off, NB, N);
  offs_kernel<<<NB, 256, 0, stream>>>(deg, bbase, off, N);
  scatter_kernel<<<(EP + tpb - 1) / tpb, tpb, 0, stream>>>(src, dst, E, N, off, cur, csr);

  int nb = (N + 63) / 64;
  // layer 1
  gemm_fused<<<nb, 128, 0, stream>>>(x, W1, as1, ad1, h, ssrc, sdst, N);
  agg_kernel<<<(N + 3) / 4, 256, 0, stream>>>(h, ssrc, sdst, off, csr, b1, t1, N, 1);
  // layer 2
  gemm_fused<<<nb, 128, 0, stream>>>(t1, W2, as2, ad2, h, ssrc, sdst, N);
  agg_kernel<<<(N + 3) / 4, 256, 0, stream>>>(h, ssrc, sdst, off, csr, b2, (float*)d_out, N, 0);
}

// Round 5
// 286.445 us; speedup vs baseline: 1.5299x; 1.1964x over previous
//
#include <hip/hip_runtime.h>
#include <hip/hip_fp16.h>

#define D 128
#define NEG_SLOPE 0.2f

// ---------------- CSR build ----------------

__global__ void hist_kernel(const int* __restrict__ dst, int E, int N, int* __restrict__ deg) {
  int i = blockIdx.x * blockDim.x + threadIdx.x;
  if (i >= E + N) return;
  int d = (i < E) ? dst[i] : (i - E);
  atomicAdd(&deg[d], 1);
}

// stage 1: per-block (256-wide) sums of deg
__global__ __launch_bounds__(256) void partial_kernel(const int* __restrict__ deg,
                                                      int* __restrict__ psum, int N) {
  __shared__ int s[256];
  int t = threadIdx.x;
  int i = blockIdx.x * 256 + t;
  s[t] = (i < N) ? deg[i] : 0;
  __syncthreads();
  #pragma unroll
  for (int o = 128; o; o >>= 1) { if (t < o) s[t] += s[t + o]; __syncthreads(); }
  if (t == 0) psum[blockIdx.x] = s[0];
}

// stage 2: scan the (<=1024) block partials in one block; also writes off[N]=total
__global__ __launch_bounds__(1024) void scan_partials(const int* __restrict__ psum,
                                                      int* __restrict__ bbase,
                                                      int* __restrict__ off, int NB, int N) {
  __shared__ int s[1024];
  int t = threadIdx.x;
  int v = (t < NB) ? psum[t] : 0;
  s[t] = v;
  __syncthreads();
  for (int o = 1; o < 1024; o <<= 1) {
    int u = (t >= o) ? s[t - o] : 0;
    __syncthreads();
    s[t] += u;
    __syncthreads();
  }
  if (t < NB) bbase[t] = s[t] - v;      // exclusive base for block t
  if (t == 1023) off[N] = s[1023];      // grand total
}

// stage 3: per-block exclusive scan + base add -> final offsets
__global__ __launch_bounds__(256) void offs_kernel(const int* __restrict__ deg,
                                                   const int* __restrict__ bbase,
                                                   int* __restrict__ off, int N) {
  __shared__ int s[256];
  int t = threadIdx.x;
  int i = blockIdx.x * 256 + t;
  int v = (i < N) ? deg[i] : 0;
  s[t] = v;
  __syncthreads();
  #pragma unroll
  for (int o = 1; o < 256; o <<= 1) {
    int u = (t >= o) ? s[t - o] : 0;
    __syncthreads();
    s[t] += u;
    __syncthreads();
  }
  if (i < N) off[i] = bbase[blockIdx.x] + s[t] - v;
}

// scatter: reuse deg as a countdown (atomicSub), no separate cursor array
__global__ void scatter_kernel(const int* __restrict__ src, const int* __restrict__ dst,
                               int E, int N, const int* __restrict__ off,
                               int* __restrict__ deg, int* __restrict__ csr) {
  int i = blockIdx.x * blockDim.x + threadIdx.x;
  if (i >= E + N) return;
  int s, d;
  if (i < E) { s = src[i]; d = dst[i]; } else { s = i - E; d = s; }
  int pos = off[d] + atomicSub(&deg[d], 1) - 1;
  csr[pos] = s;
}

// ---------------- fused GEMM + attention-score epilogue ----------------
// h = X @ W ; s_src = h @ a_src ; s_dst = h @ a_dst
// block = 256 threads (4 waves), tile = 64 rows x 128 cols, micro-tile 4x8,
// K in 4 chunks of 32.  LDS 25.1 KB.  256 threads (vs 128 in R4) doubles
// waves/CU at the grid-limited ~3 blocks/CU -> 3 waves/SIMD for latency hiding.
// H is emitted as FP16 (half2) -- only the aggregation gather consumes it.

__global__ __launch_bounds__(256, 2) void gemm_fused(
    const float* __restrict__ X, const float* __restrict__ W,
    const float* __restrict__ avs, const float* __restrict__ avd,
    __half* __restrict__ H, float* __restrict__ Ss, float* __restrict__ Sd, int N)
{
  __shared__ float At[32 * 68];   // [k][m], stride 68
  __shared__ float Ws[32 * 128];  // [k][n]
  int tid = threadIdx.x;
  int tx = tid & 15, ty = tid >> 4;     // tx: col group (16), ty: row group (16)
  int row0 = blockIdx.x * 64;

  float acc[4][8];
  #pragma unroll
  for (int i = 0; i < 4; ++i)
    #pragma unroll
    for (int j = 0; j < 8; ++j) acc[i][j] = 0.f;

  float as_[8], ad_[8];
  #pragma unroll
  for (int j = 0; j < 4; ++j) {
    as_[j]     = avs[tx * 4 + j];      ad_[j]     = avd[tx * 4 + j];
    as_[j + 4] = avs[64 + tx * 4 + j]; ad_[j + 4] = avd[64 + tx * 4 + j];
  }

  for (int kc = 0; kc < 4; ++kc) {
    // stage A chunk transposed: 64 rows x 32 k  (1024 float2 over 256 threads)
    #pragma unroll
    for (int it = 0; it < 4; ++it) {
      int lin = it * 256 + tid;        // float2 index, 0..1023
      int r = lin >> 4;                // row 0..63
      int c2 = lin & 15;               // k pair 0..15
      int gr = row0 + r;
      float2 v = make_float2(0.f, 0.f);
      if (gr < N) v = *(const float2*)&X[(size_t)gr * D + kc * 32 + c2 * 2];
      At[(c2 * 2) * 68 + r] = v.x;
      At[(c2 * 2 + 1) * 68 + r] = v.y;
    }
    // stage W chunk: 32 k x 128 n  (1024 float4, fully contiguous)
    #pragma unroll
    for (int it = 0; it < 4; ++it) {
      int lin = it * 256 + tid;        // float4 index, 0..1023
      int r = lin >> 5;                // k 0..31
      int c4 = lin & 31;
      *(float4*)&Ws[r * 128 + c4 * 4] =
          *(const float4*)&W[(size_t)(kc * 32 + r) * D + c4 * 4];
    }
    __syncthreads();
    #pragma unroll 8
    for (int k = 0; k < 32; ++k) {
      float4 a0 = *(const float4*)&At[k * 68 + ty * 4];        // rows ty*4..+3
      float4 w0 = *(const float4*)&Ws[k * 128 + tx * 4];       // cols tx*4..+3
      float4 w1 = *(const float4*)&Ws[k * 128 + 64 + tx * 4];  // cols 64+tx*4..+3
      float a[4] = {a0.x, a0.y, a0.z, a0.w};
      float wv[8] = {w0.x, w0.y, w0.z, w0.w, w1.x, w1.y, w1.z, w1.w};
      #pragma unroll
      for (int i = 0; i < 4; ++i)
        #pragma unroll
        for (int j = 0; j < 8; ++j) acc[i][j] += a[i] * wv[j];
    }
    __syncthreads();
  }

  // epilogue: write h (fp16), reduce attention scores across the 16 col-threads
  #pragma unroll
  for (int i = 0; i < 4; ++i) {
    int r = row0 + ty * 4 + i;
    bool ok = r < N;
    if (ok) {
      __half2 o0 = __floats2half2_rn(acc[i][0], acc[i][1]);
      __half2 o1 = __floats2half2_rn(acc[i][2], acc[i][3]);
      __half2 o2 = __floats2half2_rn(acc[i][4], acc[i][5]);
      __half2 o3 = __floats2half2_rn(acc[i][6], acc[i][7]);
      *(__half2*)&H[(size_t)r * D + tx * 4]          = o0;
      *(__half2*)&H[(size_t)r * D + tx * 4 + 2]      = o1;
      *(__half2*)&H[(size_t)r * D + 64 + tx * 4]     = o2;
      *(__half2*)&H[(size_t)r * D + 64 + tx * 4 + 2] = o3;
    }
    float ps = 0.f, pd = 0.f;
    #pragma unroll
    for (int j = 0; j < 8; ++j) { ps += acc[i][j] * as_[j]; pd += acc[i][j] * ad_[j]; }
    ps += __shfl_down(ps, 8); pd += __shfl_down(pd, 8);
    ps += __shfl_down(ps, 4); pd += __shfl_down(pd, 4);
    ps += __shfl_down(ps, 2); pd += __shfl_down(pd, 2);
    ps += __shfl_down(ps, 1); pd += __shfl_down(pd, 1);
    if (ok && tx == 0) { Ss[r] = ps; Sd[r] = pd; }
  }
}

// ---------------- per-dst softmax + aggregate ----------------
// one wave per dst node; lanes cover 2 channels each (one half2 = 4B/edge).
// (p,s) broadcast via __shfl with wave-uniform index; gather/FMA split x8
// keeps 8 independent loads in flight.

__global__ __launch_bounds__(256) void agg_kernel(
    const __half* __restrict__ H, const float* __restrict__ Ssrc, const float* __restrict__ Sdst,
    const int* __restrict__ off, const int* __restrict__ csr, const float* __restrict__ bias,
    float* __restrict__ out, int N, int do_relu)
{
  int wid = threadIdx.x >> 6, lane = threadIdx.x & 63;
  int n = blockIdx.x * 4 + wid;
  if (n >= N) return;
  int st = off[n], en = off[n + 1];
  float sd = Sdst[n];

  // pass 1: segment max of leaky-relu'd logits
  float m = -1e30f;
  for (int j = st + lane; j < en; j += 64) {
    int s = csr[j];
    float e = Ssrc[s] + sd;
    e = e > 0.f ? e : NEG_SLOPE * e;
    m = fmaxf(m, e);
  }
  #pragma unroll
  for (int o = 32; o; o >>= 1) m = fmaxf(m, __shfl_xor(m, o));

  // pass 2: unnormalized exp weights + gather-accumulate
  float z = 0.f, ax = 0.f, ay = 0.f;
  int c = lane * 2;
  for (int base = st; base < en; base += 64) {
    int j = base + lane;
    int cnt = min(64, en - base);        // >=1 (self-loops)
    float p = 0.f; int s = 0;
    if (j < en) {
      s = csr[j];
      float e = Ssrc[s] + sd;
      e = e > 0.f ? e : NEG_SLOPE * e;
      p = __expf(e - m);
    }
    z += p;
    for (int i = 0; i < cnt; i += 8) {
      float pu[8]; __half2 hv[8];
      #pragma unroll
      for (int u = 0; u < 8; ++u) {
        int idx = i + u;
        int iu = idx < cnt ? idx : cnt - 1;     // uniform clamp, no divergence
        float pb = __shfl(p, iu);               // v_readlane (uniform idx)
        int   sb = __shfl(s, iu);
        pu[u] = idx < cnt ? pb : 0.f;
        hv[u] = *(const __half2*)&H[(size_t)sb * D + c];
      }
      #pragma unroll
      for (int u = 0; u < 8; ++u) {
        float2 f = __half22float2(hv[u]);
        ax += pu[u] * f.x; ay += pu[u] * f.y;
      }
    }
  }
  #pragma unroll
  for (int o = 32; o; o >>= 1) z += __shfl_xor(z, o);
  float inv = 1.f / (z + 1e-16f);
  float2 bv = *(const float2*)&bias[c];
  ax = ax * inv + bv.x;
  ay = ay * inv + bv.y;
  if (do_relu) { ax = fmaxf(ax, 0.f); ay = fmaxf(ay, 0.f); }
  *(float2*)&out[(size_t)n * D + c] = make_float2(ax, ay);
}

// ---------------- launcher ----------------

extern "C" void kernel_launch(void* const* d_in, const int* in_sizes, int n_in,
                              void* d_out, int out_size, void* d_ws, size_t ws_size,
                              hipStream_t stream) {
  const float* x   = (const float*)d_in[0];
  const int*   ei  = (const int*)d_in[1];
  const float* W1  = (const float*)d_in[2];
  const float* as1 = (const float*)d_in[3];
  const float* ad1 = (const float*)d_in[4];
  const float* b1  = (const float*)d_in[5];
  const float* W2  = (const float*)d_in[6];
  const float* as2 = (const float*)d_in[7];
  const float* ad2 = (const float*)d_in[8];
  const float* b2  = (const float*)d_in[9];

  int N  = in_sizes[0] / D;
  int E  = in_sizes[1] / 2;
  int EP = E + N;
  const int* src = ei;
  const int* dst = ei + E;

  char* w = (char*)d_ws;
  auto alloc = [&](size_t bytes) -> char* {
    char* p = w; w += (bytes + 511) & ~(size_t)511; return p;
  };
  int NB = (N + 255) / 256;           // blocks for the scan stages (196)
  int*    deg   = (int*)alloc((size_t)N * 4);
  int*    off   = (int*)alloc(((size_t)N + 1) * 4);
  int*    csr   = (int*)alloc((size_t)EP * 4);
  int*    psum  = (int*)alloc((size_t)NB * 4);
  int*    bbase = (int*)alloc((size_t)NB * 4);
  float*  ssrc  = (float*)alloc((size_t)N * 4);
  float*  sdst  = (float*)alloc((size_t)N * 4);
  __half* h     = (__half*)alloc((size_t)N * D * 2);
  float*  t1    = (float*)alloc((size_t)N * D * 4);

  hipMemsetAsync(deg, 0, (size_t)N * 4, stream);

  int tpb = 256;
  hist_kernel<<<(EP + tpb - 1) / tpb, tpb, 0, stream>>>(dst, E, N, deg);
  partial_kernel<<<NB, 256, 0, stream>>>(deg, psum, N);
  scan_partials<<<1, 1024, 0, stream>>>(psum, bbase, off, NB, N);
  offs_kernel<<<NB, 256, 0, stream>>>(deg, bbase, off, N);
  scatter_kernel<<<(EP + tpb - 1) / tpb, tpb, 0, stream>>>(src, dst, E, N, off, deg, csr);

  int nb = (N + 63) / 64;
  // layer 1
  gemm_fused<<<nb, 256, 0, stream>>>(x, W1, as1, ad1, h, ssrc, sdst, N);
  agg_kernel<<<(N + 3) / 4, 256, 0, stream>>>(h, ssrc, sdst, off, csr, b1, t1, N, 1);
  // layer 2
  gemm_fused<<<nb, 256, 0, stream>>>(t1, W2, as2, ad2, h, ssrc, sdst, N);
  agg_kernel<<<(N + 3) / 4, 256, 0, stream>>>(h, ssrc, sdst, off, csr, b2, (float*)d_out, N, 0);
}

// Round 6
// 244.432 us; speedup vs baseline: 1.7928x; 1.1719x over previous
//
#include <hip/hip_runtime.h>
#include <hip/hip_fp16.h>

#define D 128
#define NEG_SLOPE 0.2f

// ---------------- CSR build (rank-based, atomic only in hist) ----------------

// stage 1: per-block (256-wide) sums of deg
__global__ __launch_bounds__(256) void partial_kernel(const int* __restrict__ deg,
                                                      int* __restrict__ psum, int N) {
  __shared__ int s[256];
  int t = threadIdx.x;
  int i = blockIdx.x * 256 + t;
  s[t] = (i < N) ? deg[i] : 0;
  __syncthreads();
  #pragma unroll
  for (int o = 128; o; o >>= 1) { if (t < o) s[t] += s[t + o]; __syncthreads(); }
  if (t == 0) psum[blockIdx.x] = s[0];
}

// stage 2: scan the (<=1024) block partials in one block; also writes off[N]=total
__global__ __launch_bounds__(1024) void scan_partials(const int* __restrict__ psum,
                                                      int* __restrict__ bbase,
                                                      int* __restrict__ off, int NB, int N) {
  __shared__ int s[1024];
  int t = threadIdx.x;
  int v = (t < NB) ? psum[t] : 0;
  s[t] = v;
  __syncthreads();
  for (int o = 1; o < 1024; o <<= 1) {
    int u = (t >= o) ? s[t - o] : 0;
    __syncthreads();
    s[t] += u;
    __syncthreads();
  }
  if (t < NB) bbase[t] = s[t] - v;      // exclusive base for block t
  if (t == 1023) off[N] = s[1023];      // grand total
}

// stage 3: per-block exclusive scan + base add -> final offsets
__global__ __launch_bounds__(256) void offs_kernel(const int* __restrict__ deg,
                                                   const int* __restrict__ bbase,
                                                   int* __restrict__ off, int N) {
  __shared__ int s[256];
  int t = threadIdx.x;
  int i = blockIdx.x * 256 + t;
  int v = (i < N) ? deg[i] : 0;
  s[t] = v;
  __syncthreads();
  #pragma unroll
  for (int o = 1; o < 256; o <<= 1) {
    int u = (t >= o) ? s[t - o] : 0;
    __syncthreads();
    s[t] += u;
    __syncthreads();
  }
  if (i < N) off[i] = bbase[blockIdx.x] + s[t] - v;
}

// scatter: atomic-free (rank precomputed in the fused hist pass)
__global__ __launch_bounds__(256) void scatter_kernel(
    const int* __restrict__ src, const int* __restrict__ dst,
    const int* __restrict__ rank, int E, int N,
    const int* __restrict__ off, int* __restrict__ csr) {
  int i = blockIdx.x * blockDim.x + threadIdx.x;
  if (i >= E + N) return;
  int s, d;
  if (i < E) { s = src[i]; d = dst[i]; } else { s = i - E; d = s; }
  csr[off[d] + rank[i]] = s;
}

// ---------------- fused GEMM(+scores) || histogram+rank ----------------
// Blocks [0, nbGemm): h = X@W, s_src = h@a_src, s_dst = h@a_dst (64x128 tile,
// 256 thr, micro-tile 4x8, K in 4 chunks of 32, LDS 25.1 KB).
// Blocks [nbGemm, nbGemm+nbHist): rank[i] = atomicAdd(&deg[dst_i], 1) --
// independent work overlapped on the same CUs (atomic-latency waves hide
// behind VALU/LDS waves).

__global__ __launch_bounds__(256, 2) void gemm_hist_fused(
    const float* __restrict__ X, const float* __restrict__ W,
    const float* __restrict__ avs, const float* __restrict__ avd,
    __half* __restrict__ H, float* __restrict__ Ss, float* __restrict__ Sd, int N,
    const int* __restrict__ dstE, int E, int* __restrict__ deg, int* __restrict__ rank,
    int nbGemm, int nbHist)
{
  if (blockIdx.x >= nbGemm) {
    if (dstE == nullptr) return;               // gemm-only launch (layer 2)
    int b = blockIdx.x - nbGemm;
    int EP = E + N;
    int stride = nbHist * 256;
    for (int i = b * 256 + (int)threadIdx.x; i < EP; i += stride) {
      int d = (i < E) ? dstE[i] : (i - E);
      rank[i] = atomicAdd(&deg[d], 1);
    }
    return;
  }

  __shared__ float At[32 * 68];   // [k][m], stride 68
  __shared__ float Ws[32 * 128];  // [k][n]
  int tid = threadIdx.x;
  int tx = tid & 15, ty = tid >> 4;     // tx: col group (16), ty: row group (16)
  int row0 = blockIdx.x * 64;

  float acc[4][8];
  #pragma unroll
  for (int i = 0; i < 4; ++i)
    #pragma unroll
    for (int j = 0; j < 8; ++j) acc[i][j] = 0.f;

  float as_[8], ad_[8];
  #pragma unroll
  for (int j = 0; j < 4; ++j) {
    as_[j]     = avs[tx * 4 + j];      ad_[j]     = avd[tx * 4 + j];
    as_[j + 4] = avs[64 + tx * 4 + j]; ad_[j + 4] = avd[64 + tx * 4 + j];
  }

  for (int kc = 0; kc < 4; ++kc) {
    // stage A chunk transposed: 64 rows x 32 k  (1024 float2 over 256 threads)
    #pragma unroll
    for (int it = 0; it < 4; ++it) {
      int lin = it * 256 + tid;        // float2 index, 0..1023
      int r = lin >> 4;                // row 0..63
      int c2 = lin & 15;               // k pair 0..15
      int gr = row0 + r;
      float2 v = make_float2(0.f, 0.f);
      if (gr < N) v = *(const float2*)&X[(size_t)gr * D + kc * 32 + c2 * 2];
      At[(c2 * 2) * 68 + r] = v.x;
      At[(c2 * 2 + 1) * 68 + r] = v.y;
    }
    // stage W chunk: 32 k x 128 n  (1024 float4, fully contiguous)
    #pragma unroll
    for (int it = 0; it < 4; ++it) {
      int lin = it * 256 + tid;        // float4 index, 0..1023
      int r = lin >> 5;                // k 0..31
      int c4 = lin & 31;
      *(float4*)&Ws[r * 128 + c4 * 4] =
          *(const float4*)&W[(size_t)(kc * 32 + r) * D + c4 * 4];
    }
    __syncthreads();
    #pragma unroll 8
    for (int k = 0; k < 32; ++k) {
      float4 a0 = *(const float4*)&At[k * 68 + ty * 4];        // rows ty*4..+3
      float4 w0 = *(const float4*)&Ws[k * 128 + tx * 4];       // cols tx*4..+3
      float4 w1 = *(const float4*)&Ws[k * 128 + 64 + tx * 4];  // cols 64+tx*4..+3
      float a[4] = {a0.x, a0.y, a0.z, a0.w};
      float wv[8] = {w0.x, w0.y, w0.z, w0.w, w1.x, w1.y, w1.z, w1.w};
      #pragma unroll
      for (int i = 0; i < 4; ++i)
        #pragma unroll
        for (int j = 0; j < 8; ++j) acc[i][j] += a[i] * wv[j];
    }
    __syncthreads();
  }

  // epilogue: write h (fp16), reduce attention scores across the 16 col-threads
  #pragma unroll
  for (int i = 0; i < 4; ++i) {
    int r = row0 + ty * 4 + i;
    bool ok = r < N;
    if (ok) {
      __half2 o0 = __floats2half2_rn(acc[i][0], acc[i][1]);
      __half2 o1 = __floats2half2_rn(acc[i][2], acc[i][3]);
      __half2 o2 = __floats2half2_rn(acc[i][4], acc[i][5]);
      __half2 o3 = __floats2half2_rn(acc[i][6], acc[i][7]);
      *(__half2*)&H[(size_t)r * D + tx * 4]          = o0;
      *(__half2*)&H[(size_t)r * D + tx * 4 + 2]      = o1;
      *(__half2*)&H[(size_t)r * D + 64 + tx * 4]     = o2;
      *(__half2*)&H[(size_t)r * D + 64 + tx * 4 + 2] = o3;
    }
    float ps = 0.f, pd = 0.f;
    #pragma unroll
    for (int j = 0; j < 8; ++j) { ps += acc[i][j] * as_[j]; pd += acc[i][j] * ad_[j]; }
    ps += __shfl_down(ps, 8); pd += __shfl_down(pd, 8);
    ps += __shfl_down(ps, 4); pd += __shfl_down(pd, 4);
    ps += __shfl_down(ps, 2); pd += __shfl_down(pd, 2);
    ps += __shfl_down(ps, 1); pd += __shfl_down(pd, 1);
    if (ok && tx == 0) { Ss[r] = ps; Sd[r] = pd; }
  }
}

// ---------------- per-dst softmax + aggregate ----------------
// one wave per dst node; lanes cover 2 channels each (one half2 = 4B/edge).
// (p,s) broadcast via __shfl with wave-uniform index; gather/FMA split x8
// keeps 8 independent loads in flight.

__global__ __launch_bounds__(256) void agg_kernel(
    const __half* __restrict__ H, const float* __restrict__ Ssrc, const float* __restrict__ Sdst,
    const int* __restrict__ off, const int* __restrict__ csr, const float* __restrict__ bias,
    float* __restrict__ out, int N, int do_relu)
{
  int wid = threadIdx.x >> 6, lane = threadIdx.x & 63;
  int n = blockIdx.x * 4 + wid;
  if (n >= N) return;
  int st = off[n], en = off[n + 1];
  float sd = Sdst[n];

  // pass 1: segment max of leaky-relu'd logits
  float m = -1e30f;
  for (int j = st + lane; j < en; j += 64) {
    int s = csr[j];
    float e = Ssrc[s] + sd;
    e = e > 0.f ? e : NEG_SLOPE * e;
    m = fmaxf(m, e);
  }
  #pragma unroll
  for (int o = 32; o; o >>= 1) m = fmaxf(m, __shfl_xor(m, o));

  // pass 2: unnormalized exp weights + gather-accumulate
  float z = 0.f, ax = 0.f, ay = 0.f;
  int c = lane * 2;
  for (int base = st; base < en; base += 64) {
    int j = base + lane;
    int cnt = min(64, en - base);        // >=1 (self-loops)
    float p = 0.f; int s = 0;
    if (j < en) {
      s = csr[j];
      float e = Ssrc[s] + sd;
      e = e > 0.f ? e : NEG_SLOPE * e;
      p = __expf(e - m);
    }
    z += p;
    for (int i = 0; i < cnt; i += 8) {
      float pu[8]; __half2 hv[8];
      #pragma unroll
      for (int u = 0; u < 8; ++u) {
        int idx = i + u;
        int iu = idx < cnt ? idx : cnt - 1;     // uniform clamp, no divergence
        float pb = __shfl(p, iu);               // v_readlane (uniform idx)
        int   sb = __shfl(s, iu);
        pu[u] = idx < cnt ? pb : 0.f;
        hv[u] = *(const __half2*)&H[(size_t)sb * D + c];
      }
      #pragma unroll
      for (int u = 0; u < 8; ++u) {
        float2 f = __half22float2(hv[u]);
        ax += pu[u] * f.x; ay += pu[u] * f.y;
      }
    }
  }
  #pragma unroll
  for (int o = 32; o; o >>= 1) z += __shfl_xor(z, o);
  float inv = 1.f / (z + 1e-16f);
  float2 bv = *(const float2*)&bias[c];
  ax = ax * inv + bv.x;
  ay = ay * inv + bv.y;
  if (do_relu) { ax = fmaxf(ax, 0.f); ay = fmaxf(ay, 0.f); }
  *(float2*)&out[(size_t)n * D + c] = make_float2(ax, ay);
}

// ---------------- launcher ----------------

extern "C" void kernel_launch(void* const* d_in, const int* in_sizes, int n_in,
                              void* d_out, int out_size, void* d_ws, size_t ws_size,
                              hipStream_t stream) {
  const float* x   = (const float*)d_in[0];
  const int*   ei  = (const int*)d_in[1];
  const float* W1  = (const float*)d_in[2];
  const float* as1 = (const float*)d_in[3];
  const float* ad1 = (const float*)d_in[4];
  const float* b1  = (const float*)d_in[5];
  const float* W2  = (const float*)d_in[6];
  const float* as2 = (const float*)d_in[7];
  const float* ad2 = (const float*)d_in[8];
  const float* b2  = (const float*)d_in[9];

  int N  = in_sizes[0] / D;
  int E  = in_sizes[1] / 2;
  int EP = E + N;
  const int* src = ei;
  const int* dst = ei + E;

  char* w = (char*)d_ws;
  auto alloc = [&](size_t bytes) -> char* {
    char* p = w; w += (bytes + 511) & ~(size_t)511; return p;
  };
  int NB = (N + 255) / 256;           // blocks for the scan stages (196)
  int*    deg   = (int*)alloc((size_t)N * 4);
  int*    off   = (int*)alloc(((size_t)N + 1) * 4);
  int*    csr   = (int*)alloc((size_t)EP * 4);
  int*    rank  = (int*)alloc((size_t)EP * 4);
  int*    psum  = (int*)alloc((size_t)NB * 4);
  int*    bbase = (int*)alloc((size_t)NB * 4);
  float*  ssrc  = (float*)alloc((size_t)N * 4);
  float*  sdst  = (float*)alloc((size_t)N * 4);
  __half* h     = (__half*)alloc((size_t)N * D * 2);
  float*  t1    = (float*)alloc((size_t)N * D * 4);

  hipMemsetAsync(deg, 0, (size_t)N * 4, stream);

  int nbGemm = (N + 63) / 64;         // 782
  int nbHist = 1024;

  // layer-1 GEMM overlapped with histogram+rank (independent work)
  gemm_hist_fused<<<nbGemm + nbHist, 256, 0, stream>>>(
      x, W1, as1, ad1, h, ssrc, sdst, N, dst, E, deg, rank, nbGemm, nbHist);

  // offsets + atomic-free scatter
  partial_kernel<<<NB, 256, 0, stream>>>(deg, psum, N);
  scan_partials<<<1, 1024, 0, stream>>>(psum, bbase, off, NB, N);
  offs_kernel<<<NB, 256, 0, stream>>>(deg, bbase, off, N);
  scatter_kernel<<<(EP + 255) / 256, 256, 0, stream>>>(src, dst, rank, E, N, off, csr);

  // layer 1 aggregate
  agg_kernel<<<(N + 3) / 4, 256, 0, stream>>>(h, ssrc, sdst, off, csr, b1, t1, N, 1);
  // layer 2
  gemm_hist_fused<<<nbGemm, 256, 0, stream>>>(
      t1, W2, as2, ad2, h, ssrc, sdst, N, nullptr, 0, nullptr, nullptr, nbGemm, 0);
  agg_kernel<<<(N + 3) / 4, 256, 0, stream>>>(h, ssrc, sdst, off, csr, b2, (float*)d_out, N, 0);
}